// Round 4
// baseline (137.245 us; speedup 1.0000x reference)
//
#include <hip/hip_runtime.h>
#include <math.h>

// Problem constants (RelTransformerActor)
namespace {
constexpr int B_  = 128;
constexpr int T_  = 128;
constexpr int K_  = 8;
constexpr int H_  = 3;
constexpr int HK_ = 24;
constexpr int HID_ = 256;
constexpr int OUT_ = 2;
constexpr int PBS_ = 136;  // P row stride (bf16): 272B -> 2-way bank spread
constexpr int X1S_ = 264;  // x1 row stride (bf16): 528B
constexpr int STS_ = 132;  // St row stride (bf16): 264B -> distinct banks per d
constexpr int NPROD_ = 17; // blocks 0..15: W2 slices; block 16: fused W1''
}

typedef __attribute__((ext_vector_type(8))) short bf16x8;
typedef __attribute__((ext_vector_type(4))) float f32x4;

__device__ inline unsigned short f2bf(float x) {           // RNE fp32->bf16
    unsigned int u = __float_as_uint(x);
    u += 0x7FFFu + ((u >> 16) & 1u);
    return (unsigned short)(u >> 16);
}
__device__ inline float bf2f(unsigned short v) { return __uint_as_float((unsigned)v << 16); }

// Cross-lane add via DPP (VALU pipe, not DS).
template <int CTRL>
__device__ inline float dpp_add(float v) {
    int t = __builtin_amdgcn_update_dpp(0, __float_as_int(v), CTRL, 0xF, 0xF, true);
    return v + __int_as_float(t);
}
__device__ inline float red16(float v) {   // sum over 16-lane groups (all lanes get it)
    v = dpp_add<0xB1>(v);     // quad_perm lane^1
    v = dpp_add<0x4E>(v);     // quad_perm lane^2
    v = dpp_add<0x141>(v);    // row_half_mirror
    return dpp_add<0x140>(v); // row_mirror
}

// ---------------------------------------------------------------------------
// Algebraic fusion (exact identities, bf16 rounding points only change):
//   keys:  k_{i,j} = (s_j - s_i)Wk; scores = q_i.k_j = q_i.(s_j Wk) - const_i
//          -> softmax shift-invariance drops const_i; with U_i = (q_i Wk^T)/sqrt8,
//             scores_ij = U_i . s_j  => NO K projection, K staging = raw state.
//   vals:  sum_j w_ij (s_j - s_i)Wv = (sum_j w_ij s_j - s_i)Wv = A_i Wv
//          -> PV runs against raw state; Wv folds into W1 on the producer side:
//             W1''[h*8+d,:] = sum_e Wv[d,h8+e] * W1[h8+e,:]  (f32 precompute)
//          => NO V projection, x1 = [A^0,A^1,A^2,s_i] @ W1''.
// Structure: 256 blocks x 512 threads (8 waves). Group g = w>>1 owns rows
// [g*16,g*16+16); wave pair splits by HEAD (c=0: h{0,1}, c=1: h{2}) so P is
// wave-private (no barrier inside attention); row-sums l stay in registers
// (red16 leaves l in exactly the lanes the PV epilogue needs).
// Barriers: 4 (was 6). Producers inlined in blocks 0..16; all blocks spin on
// flags before x1. Grid=256 <= 256 CUs -> co-resident -> spin deadlock-safe.
// ---------------------------------------------------------------------------
__global__ __launch_bounds__(512, 1) void fused_actor_kernel(
    const float* __restrict__ state,
    const float* __restrict__ noise,
    const float* __restrict__ Wq, const float* __restrict__ Wk,
    const float* __restrict__ Wv,
    const float* __restrict__ W1, const float* __restrict__ b1,
    const float* __restrict__ W2, const float* __restrict__ b2,
    const float* __restrict__ Wmu, const float* __restrict__ bmu,
    const float* __restrict__ Wls, const float* __restrict__ bls,
    unsigned short* __restrict__ w1t, unsigned short* __restrict__ w2t,
    unsigned int* __restrict__ flags,
    float* __restrict__ out)
{
    __shared__ alignas(16) unsigned short Sb[T_][8];         // 2 KB  state bf16
    __shared__ alignas(16) unsigned short St[K_][STS_];      // 2.06 KB state^T
    __shared__ union alignas(16) UH {                        // 8 KB
        unsigned short Ua[64][40];     // U rows (cols 0-23), live P1->scores
        float hp[8][64][4];            // heads->tail (after 2 barriers)
    } uh;
    __shared__ alignas(16) unsigned short a0b[64][40];       // 5 KB  [A||s_i]
    __shared__ union alignas(16) Arena {                     // 34 KB
        unsigned short P[8][16][PBS_];   // per-WAVE, scores->PS
        unsigned short x1[4][16][X1S_];  // per-group, x1->x2
    } arena;
    // total ~51 KB static; 1 block/CU, 8 waves/CU.

    const int tid = threadIdx.x;
    const int blk = blockIdx.x;

    // ---- inline producers: blocks 0..15 W2->bf16; block 16 W1'' fold ----
    if (blk < NPROD_) {
        if (blk < 16) {
            unsigned short tmp[8];
            const int n = tid & 255;
            const int k0 = blk*16 + (tid >> 8)*8;
            #pragma unroll
            for (int i = 0; i < 8; ++i) tmp[i] = f2bf(W2[(size_t)(k0+i)*HID_ + n]);
            *(bf16x8*)(w2t + (size_t)n*256 + k0) = *(const bf16x8*)tmp;
        } else {
            // W1''[c,n]: c<24 -> G_h[d,n] = sum_e Wv[d,h8+e]*W1[h8+e,n]; c>=24 -> W1[c,n]
            const int n = tid & 255;
            const int c0 = (tid >> 8) * 16;
            for (int cc = c0; cc < c0 + 16; ++cc) {
                float v;
                if (cc < 24) {
                    const int h8 = cc & ~7, d = cc & 7;
                    v = 0.f;
                    #pragma unroll
                    for (int e = 0; e < 8; ++e)
                        v = fmaf(Wv[d*HK_ + h8 + e], W1[(size_t)(h8+e)*HID_ + n], v);
                } else {
                    v = W1[(size_t)cc*HID_ + n];
                }
                w1t[(size_t)n*32 + cc] = f2bf(v);
            }
        }
        __syncthreads();               // all block stores issued
        if (tid == 0) {
            __threadfence();           // writes visible device-wide
            __hip_atomic_store(&flags[blk], 1u, __ATOMIC_RELEASE,
                               __HIP_MEMORY_SCOPE_AGENT);
        }
    }

    const int b    = blk >> 1;
    const int i0   = (blk & 1) * 64;             // 64-row slice of T
    const int w    = tid >> 6;                   // wave 0..7
    const int g    = w >> 1;                     // row-group 0..3
    const int c    = w & 1;                      // head-half within group
    const int lq   = (tid >> 4) & 3;   // MFMA quad: k-chunk (A/B) / row-group (C/D)
    const int ln   = tid & 15;         // MFMA m (A) / n (B, C/D cols)
    const float* sb = state + (size_t)b*T_*K_;

    // ---- prefetch input-resident biases/head weights into registers ----
    float b1v[8];
    #pragma unroll
    for (int nt = 0; nt < 8; ++nt) b1v[nt] = b1[(c*8 + nt)*16 + ln];
    float b2v[2];
    float2 wmv[2], wlv[2];
    #pragma unroll
    for (int nt = 0; nt < 2; ++nt) {
        const int n0 = (w*2 + nt)*16 + ln;
        b2v[nt] = b2[n0];
        wmv[nt] = *(const float2*)(Wmu + n0*OUT_);
        wlv[nt] = *(const float2*)(Wls + n0*OUT_);
    }

    // ---- P1: stage state (Sb/St), compute U rows, stage s_i into a0b ----
    if (tid < 128) {
        const int j = tid;
        const float4 s0 = *(const float4*)(sb + j*8);
        const float4 s1 = *(const float4*)(sb + j*8 + 4);
        const float sv[8] = {s0.x,s0.y,s0.z,s0.w,s1.x,s1.y,s1.z,s1.w};
        unsigned short pk[8];
        #pragma unroll
        for (int k = 0; k < 8; ++k) pk[k] = f2bf(sv[k]);
        *(bf16x8*)&Sb[j][0] = *(const bf16x8*)pk;
        #pragma unroll
        for (int d = 0; d < 8; ++d) St[d][j] = pk[d];
    } else if (tid < 320) {
        // U^h_i = (s_i Wq_h) Wk_h^T / sqrt(8): thread = (row il, head h)
        const int t2 = tid - 128;
        const int il = t2 & 63;
        const int h8 = (t2 >> 6) * 8;
        const float4 s0 = *(const float4*)(sb + (i0+il)*8);
        const float4 s1 = *(const float4*)(sb + (i0+il)*8 + 4);
        const float sv[8] = {s0.x,s0.y,s0.z,s0.w,s1.x,s1.y,s1.z,s1.w};
        float q[8];
        #pragma unroll
        for (int cc = 0; cc < 8; ++cc) {
            float a = 0.f;
            #pragma unroll
            for (int m = 0; m < K_; ++m) a = fmaf(sv[m], Wq[m*HK_ + h8 + cc], a);
            q[cc] = a * 0.35355339059327373f;
        }
        unsigned short uu[8];
        #pragma unroll
        for (int d = 0; d < 8; ++d) {
            float u = 0.f;
            #pragma unroll
            for (int cc = 0; cc < 8; ++cc) u = fmaf(q[cc], Wk[d*HK_ + h8 + cc], u);
            uu[d] = f2bf(u);
        }
        *(bf16x8*)&uh.Ua[il][h8] = *(const bf16x8*)uu;
    } else if (tid < 384) {
        const int il = tid - 320;
        const float4 s0 = *(const float4*)(sb + (i0+il)*8);
        const float4 s1 = *(const float4*)(sb + (i0+il)*8 + 4);
        const float sv[8] = {s0.x,s0.y,s0.z,s0.w,s1.x,s1.y,s1.z,s1.w};
        unsigned short pk[8];
        #pragma unroll
        for (int k = 0; k < 8; ++k) pk[k] = f2bf(sv[k]);
        *(bf16x8*)&a0b[il][24] = *(const bf16x8*)pk;
    }
    __syncthreads();                                   // barrier 1

    // ================= attention: wave-private, no internal barrier =========
    const int rw = g*16;
    {
        const bf16x8 zf = {0,0,0,0,0,0,0,0};
        const f32x4 c0v = {0.f,0.f,0.f,0.f};
        const int hbeg = c ? 2 : 0;
        const int hend = c ? 3 : 2;
        for (int h = hbeg; h < hend; ++h) {
            // scores_h = U_h . s_j (8 MFMAs over full j), exp+mask, P, row-sums
            const bf16x8 tq = *(const bf16x8*)&uh.Ua[rw + ln][h*8];
            const bf16x8 qa = (lq == 0) ? tq : zf;
            float esum[4] = {0.f, 0.f, 0.f, 0.f};
            #pragma unroll
            for (int nt = 0; nt < 8; ++nt) {
                const bf16x8 tb = *(const bf16x8*)&Sb[nt*16 + ln][0];
                const bf16x8 kf = (lq == 0) ? tb : zf;
                f32x4 s = __builtin_amdgcn_mfma_f32_16x16x32_bf16(qa, kf, c0v, 0,0,0);
                #pragma unroll
                for (int r = 0; r < 4; ++r) {
                    const int rl = lq*4 + r;
                    const int j  = nt*16 + ln;
                    const float e = (j == i0 + rw + rl) ? 0.f : __expf(s[r]);
                    esum[r] += e;
                    arena.P[w][rl][j] = f2bf(e);
                }
            }
            #pragma unroll
            for (int r = 0; r < 4; ++r) esum[r] = red16(esum[r]);  // l in-reg

            // A^h = (P @ S)/l - s_i   (4 MFMAs; same-wave LDS RAW via lgkmcnt)
            f32x4 x = {0.f, 0.f, 0.f, 0.f};
            #pragma unroll
            for (int ks = 0; ks < 4; ++ks) {
                const bf16x8 pa = *(const bf16x8*)&arena.P[w][ln][ks*32 + lq*8];
                const bf16x8 tv = *(const bf16x8*)&St[ln & 7][ks*32 + lq*8];
                const bf16x8 vf = (ln < 8) ? tv : zf;
                x = __builtin_amdgcn_mfma_f32_16x16x32_bf16(pa, vf, x, 0, 0, 0);
            }
            if (ln < 8) {
                #pragma unroll
                for (int r = 0; r < 4; ++r) {
                    const int rl = lq*4 + r;
                    const float a = x[r] / esum[r] - bf2f(Sb[i0 + rw + rl][ln]);
                    a0b[rw + rl][h*8 + ln] = f2bf(a);
                }
            }
        }
    }

    // ---- acquire producer flags (prep overlapped P1+attention) ----
    if (tid < NPROD_) {
        while (__hip_atomic_load(&flags[tid], __ATOMIC_ACQUIRE,
                                 __HIP_MEMORY_SCOPE_AGENT) != 1u) {
            __builtin_amdgcn_s_sleep(1);
        }
    }
    __syncthreads();                  // barrier 2 (flags + a0b + arena reuse)

    // ---- x1 = relu([A||s] @ W1'' + b1): 8 MFMAs/wave (N-half) ----
    {
        bf16x8 w1f[8];
        #pragma unroll
        for (int nt = 0; nt < 8; ++nt)
            w1f[nt] = *(const bf16x8*)(w1t + (size_t)((c*8+nt)*16+ln)*32 + lq*8);
        const bf16x8 a0 = *(const bf16x8*)&a0b[rw + ln][lq*8];
        #pragma unroll
        for (int nt = 0; nt < 8; ++nt) {
            const float bias = b1v[nt];
            f32x4 cc = {bias, bias, bias, bias};
            f32x4 d = __builtin_amdgcn_mfma_f32_16x16x32_bf16(a0, w1f[nt], cc, 0, 0, 0);
            #pragma unroll
            for (int r = 0; r < 4; ++r)
                arena.x1[g][lq*4 + r][(c*8+nt)*16 + ln] = f2bf(fmaxf(d[r], 0.f));
        }
    }
    __syncthreads();                                   // barrier 3

    // ---- x2 = relu(x1 @ W2 + b2): M=64 (4 m-tiles), wave's N=32 slice ----
    f32x4 acc2[4][2];                      // [mt][nt]
    #pragma unroll
    for (int nt = 0; nt < 2; ++nt) {
        const float bias = b2v[nt];
        f32x4 cc = {bias, bias, bias, bias};
        #pragma unroll
        for (int mt = 0; mt < 4; ++mt) acc2[mt][nt] = cc;
    }
    #pragma unroll
    for (int ks = 0; ks < 8; ++ks) {
        bf16x8 a[4];
        #pragma unroll
        for (int mt = 0; mt < 4; ++mt)
            a[mt] = *(const bf16x8*)&arena.x1[mt][ln][ks*32 + lq*8];
        #pragma unroll
        for (int nt = 0; nt < 2; ++nt) {
            const bf16x8 bf = *(const bf16x8*)(w2t + (size_t)((w*2+nt)*16+ln)*256 + ks*32 + lq*8);
            #pragma unroll
            for (int mt = 0; mt < 4; ++mt)
                acc2[mt][nt] = __builtin_amdgcn_mfma_f32_16x16x32_bf16(a[mt], bf, acc2[mt][nt], 0,0,0);
        }
    }

    // ---- heads: relu(x2).{Wmu,Wls}; DPP 16-lane reduce over n-lanes ----
    {
        float p[4][4][4];                  // [mt][r][o]
        #pragma unroll
        for (int mt = 0; mt < 4; ++mt)
            #pragma unroll
            for (int r = 0; r < 4; ++r)
                #pragma unroll
                for (int o = 0; o < 4; ++o) p[mt][r][o] = 0.f;
        #pragma unroll
        for (int nt = 0; nt < 2; ++nt) {
            const float2 wm = wmv[nt];
            const float2 wl = wlv[nt];
            #pragma unroll
            for (int mt = 0; mt < 4; ++mt) {
                #pragma unroll
                for (int r = 0; r < 4; ++r) {
                    const float x2 = fmaxf(acc2[mt][nt][r], 0.f);
                    p[mt][r][0] = fmaf(x2, wm.x, p[mt][r][0]);
                    p[mt][r][1] = fmaf(x2, wm.y, p[mt][r][1]);
                    p[mt][r][2] = fmaf(x2, wl.x, p[mt][r][2]);
                    p[mt][r][3] = fmaf(x2, wl.y, p[mt][r][3]);
                }
            }
        }
        #pragma unroll
        for (int mt = 0; mt < 4; ++mt)
            #pragma unroll
            for (int r = 0; r < 4; ++r)
                #pragma unroll
                for (int o = 0; o < 4; ++o)
                    p[mt][r][o] = red16(p[mt][r][o]);
        if (ln == 0) {
            #pragma unroll
            for (int mt = 0; mt < 4; ++mt)
                #pragma unroll
                for (int r = 0; r < 4; ++r) {
                    f32x4 pv = {p[mt][r][0], p[mt][r][1], p[mt][r][2], p[mt][r][3]};
                    *(f32x4*)&uh.hp[w][mt*16 + lq*4 + r][0] = pv;
                }
        }
    }
    __syncthreads();                                   // barrier 4

    // ---- sampling tail: one thread per row ----
    if (tid < 64) {
        const int r = tid;
        const int grow = b*T_ + i0 + r;
        float pre[4];
        #pragma unroll
        for (int o = 0; o < 4; ++o) {
            float s = 0.f;
            #pragma unroll
            for (int ww = 0; ww < 8; ++ww) s += uh.hp[ww][r][o];
            pre[o] = s;
        }
        float lp = 0.f;
        #pragma unroll
        for (int o = 0; o < OUT_; ++o) {
            float mu  = tanhf(pre[o]   + bmu[o]);
            float lsp = tanhf(pre[2+o] + bls[o]);
            float log_std = -20.f + 11.f * (lsp + 1.f);
            float sd = __expf(log_std);
            float n  = noise[(size_t)grow*OUT_ + o];
            float z  = fmaf(sd, n, mu);
            float a  = tanhf(z);
            out[(size_t)grow*OUT_ + o] = a;
            lp += -0.5f*n*n - log_std - 0.91893853320467274f
                  - logf(1.f - a*a + 1e-7f);
        }
        out[(size_t)B_*T_*OUT_ + grow] = lp;
    }
}

extern "C" void kernel_launch(void* const* d_in, const int* in_sizes, int n_in,
                              void* d_out, int out_size, void* d_ws, size_t ws_size,
                              hipStream_t stream)
{
    const float* state = (const float*)d_in[0];
    const float* noise = (const float*)d_in[1];
    const float* Wq  = (const float*)d_in[2];
    const float* Wk  = (const float*)d_in[3];
    const float* Wv  = (const float*)d_in[4];
    const float* W1  = (const float*)d_in[5];
    const float* b1  = (const float*)d_in[6];
    const float* W2  = (const float*)d_in[7];
    const float* b2  = (const float*)d_in[8];
    const float* Wmu = (const float*)d_in[9];
    const float* bmu = (const float*)d_in[10];
    const float* Wls = (const float*)d_in[11];
    const float* bls = (const float*)d_in[12];
    float* out = (float*)d_out;

    unsigned short* w1t = (unsigned short*)d_ws;            // 8192 bf16 = 16 KB (W1'')
    unsigned short* w2t = w1t + 8192;                       // 65536 bf16 = 128 KB
    unsigned int*  flags = (unsigned int*)(w2t + 65536);    // 17 cells (poison != 1)

    fused_actor_kernel<<<dim3(B_*2), dim3(512), 0, stream>>>(
        state, noise, Wq, Wk, Wv, W1, b1, W2, b2, Wmu, bmu, Wls, bls,
        w1t, w2t, flags, out);
}

// Round 5
// 92.281 us; speedup vs baseline: 1.4873x; 1.4873x over previous
//
#include <hip/hip_runtime.h>
#include <math.h>

// Problem constants (RelTransformerActor)
namespace {
constexpr int B_  = 128;
constexpr int T_  = 128;
constexpr int K_  = 8;
constexpr int H_  = 3;
constexpr int HK_ = 24;
constexpr int HID_ = 256;
constexpr int OUT_ = 2;
constexpr int PBS_ = 136;  // P row stride (bf16): 272B, 16B-aligned, banks spread
constexpr int X1S_ = 264;  // x1 row stride (bf16): 528B
constexpr int NPROD_ = 17; // blocks 0..15: W2 16-row slices; block 16: W1
}

typedef __attribute__((ext_vector_type(8))) short bf16x8;
typedef __attribute__((ext_vector_type(4))) float f32x4;

__device__ inline unsigned short f2bf(float x) {           // RNE fp32->bf16
    unsigned int u = __float_as_uint(x);
    u += 0x7FFFu + ((u >> 16) & 1u);
    return (unsigned short)(u >> 16);
}
__device__ inline float bf2f(unsigned short v) { return __uint_as_float((unsigned)v << 16); }

// Fast tanh via hardware exp: tanh(x) = 1 - 2/(e^{2x}+1).
// Saturates correctly for |x| large (e -> inf or 0); ~1e-6 rel accuracy.
__device__ inline float ftanh(float x) {
    const float e = __expf(2.f * x);
    return 1.f - 2.f / (e + 1.f);
}

// Cross-lane add via DPP (VALU pipe, not DS).
template <int CTRL>
__device__ inline float dpp_add(float v) {
    int t = __builtin_amdgcn_update_dpp(0, __float_as_int(v), CTRL, 0xF, 0xF, true);
    return v + __int_as_float(t);
}
__device__ inline float red16(float v) {   // sum over 16-lane groups
    v = dpp_add<0xB1>(v);     // quad_perm lane^1
    v = dpp_add<0x4E>(v);     // quad_perm lane^2
    v = dpp_add<0x141>(v);    // row_half_mirror
    return dpp_add<0x140>(v); // row_mirror
}

// ---------------------------------------------------------------------------
// Single-launch, 256 blocks x 512 threads (8 waves). Block = (b, half of T):
// 64 rows. Row-group g = w>>1 owns rows [g*16, g*16+16); the TWO waves of a
// group (c = w&1) split work along j/N/heads:
//   QK^T : wave c does nt = c*4..c*4+3 (j-half), partial row-sums in lsw[g][c]
//   PV   : c=0 -> heads {0,1}, c=1 -> head {2} (full j, P shared post-barrier)
//   x1   : wave c does n-tiles c*8..c*8+7
//   x2   : wave w does N-slice [w*32, w*32+32)
//   proj : waves 0-3 (tid<256) K/V, waves 4-7 Q
// First NPROD_ blocks additionally convert W2/W1 -> bf16 workspace up front
// and release flags; all blocks acquire-spin before x1 (flags are set within
// ~µs, spin happens ~tens of µs in). Grid = 256 = 1 block/CU -> all blocks
// trivially co-resident -> spin is deadlock-safe unconditionally.
// This is the measured champion structure (json 92.7 µs; kernel ~12 µs after
// subtracting the harness's 2x40 µs workspace poison fills). Round-4's
// algebraic rewrite (U-trick + head-split + W1'' fold) regressed the kernel
// to 66 µs steady-state -> reverted.
// ---------------------------------------------------------------------------
__global__ __launch_bounds__(512, 2) void fused_actor_kernel(
    const float* __restrict__ state,
    const float* __restrict__ noise,
    const float* __restrict__ Wq, const float* __restrict__ Wk,
    const float* __restrict__ Wv,
    const float* __restrict__ W1, const float* __restrict__ b1,
    const float* __restrict__ W2, const float* __restrict__ b2,
    const float* __restrict__ Wmu, const float* __restrict__ bmu,
    const float* __restrict__ Wls, const float* __restrict__ bls,
    unsigned short* __restrict__ w1t, unsigned short* __restrict__ w2t,
    unsigned int* __restrict__ flags,
    float* __restrict__ out)
{
    __shared__ float wq_s[K_*HK_], wk_s[K_*HK_], wv_s[K_*HK_]; // 2.25 KB
    __shared__ union alignas(16) QH {                        // 8 KB
        unsigned short Qb[64][HK_];    // live: projections -> QK^T
        float hp[8][64][4];            // live: heads -> tail (after barriers)
    } qh;
    __shared__ alignas(16) unsigned short Kb[H_][T_][8];     // 6 KB
    __shared__ alignas(16) unsigned short Vt[H_][K_][T_];    // 6 KB
    __shared__ alignas(16) float lsw[4][2][H_][16];          // 1.5 KB
    __shared__ alignas(16) unsigned short a0b[64][40];       // 5 KB
    __shared__ union alignas(16) Arena {                     // per-group arena
        unsigned short P[16][PBS_];                          // 4.25 KB
        unsigned short x1[16][X1S_];                         // 8.25 KB
    } arena[4];                                              // 33 KB
    // total ~61.75 KB static (< 64 KB limit); 1 block/CU.

    const int tid = threadIdx.x;
    const int blk = blockIdx.x;

    // ---- inline producers: first 17 blocks convert W2/W1 to bf16 ----
    if (blk < NPROD_) {
        unsigned short tmp[8];
        const int n = tid & 255;
        if (blk < 16) {
            const int k0 = blk*16 + (tid >> 8)*8;
            #pragma unroll
            for (int i = 0; i < 8; ++i) tmp[i] = f2bf(W2[(size_t)(k0+i)*HID_ + n]);
            *(bf16x8*)(w2t + (size_t)n*256 + k0) = *(const bf16x8*)tmp;
        } else {
            for (int cc = tid >> 8; cc < 4; cc += 2) {
                const int k0 = cc*8;
                #pragma unroll
                for (int i = 0; i < 8; ++i) tmp[i] = f2bf(W1[(size_t)(k0+i)*HID_ + n]);
                *(bf16x8*)(w1t + (size_t)n*32 + k0) = *(const bf16x8*)tmp;
            }
        }
        __syncthreads();               // all block stores issued
        if (tid == 0) {
            __threadfence();           // writes visible device-wide
            __hip_atomic_store(&flags[blk], 1u, __ATOMIC_RELEASE,
                               __HIP_MEMORY_SCOPE_AGENT);
        }
    }

    const int b    = blk >> 1;
    const int i0   = (blk & 1) * 64;             // 64-row slice of T
    const int w    = tid >> 6;                   // wave 0..7
    const int g    = w >> 1;                     // row-group 0..3
    const int c    = w & 1;                      // work-half within group
    const int lq   = (tid >> 4) & 3;   // MFMA quad: k-chunk (A/B) / row-group (C/D)
    const int ln   = tid & 15;         // MFMA m (A) / n (B, C/D cols)
    const float* sb = state + (size_t)b*T_*K_;

    // ---- stage qkv weights; prefetch input-resident biases/head weights ----
    if (tid < K_*HK_) { wq_s[tid]=Wq[tid]; wk_s[tid]=Wk[tid]; wv_s[tid]=Wv[tid]; }
    float b1v[8];
    #pragma unroll
    for (int nt = 0; nt < 8; ++nt) b1v[nt] = b1[(c*8 + nt)*16 + ln];
    float b2v[2];
    float2 wmv[2], wlv[2];
    #pragma unroll
    for (int nt = 0; nt < 2; ++nt) {
        const int n0 = (w*2 + nt)*16 + ln;
        b2v[nt] = b2[n0];
        wmv[nt] = *(const float2*)(Wmu + n0*OUT_);
        wlv[nt] = *(const float2*)(Wls + n0*OUT_);
    }
    __syncthreads();                                   // barrier 1

    // ---- projections: waves 0-3 do K/V (all 128 j), waves 4-7 do Q ----
    if (tid < 256) {
        const int j = tid >> 1, p = tid & 1;
        const float4 s0 = *(const float4*)(sb + j*8);
        const float4 s1 = *(const float4*)(sb + j*8 + 4);
        const float sv[8] = {s0.x,s0.y,s0.z,s0.w,s1.x,s1.y,s1.z,s1.w};
        const float* ws = p ? wv_s : wk_s;
        #pragma unroll
        for (int h = 0; h < H_; ++h) {
            unsigned short pk[8];
            #pragma unroll
            for (int k = 0; k < 8; ++k) {
                const int col = h*8 + k;
                float a = 0.f;
                #pragma unroll
                for (int m = 0; m < K_; ++m) a = fmaf(sv[m], ws[m*HK_+col], a);
                pk[k] = f2bf(a);
            }
            if (p == 0) {
                *(bf16x8*)&Kb[h][j][0] = *(const bf16x8*)pk;
            } else {
                #pragma unroll
                for (int d = 0; d < 8; ++d) Vt[h][d][j] = pk[d];  // transposed V
            }
        }
        // concat-state columns of a0b (block's 64 rows), bf16-packed
        if (p == 0 && j >= i0 && j < i0 + 64) {
            unsigned short sb16[8];
            #pragma unroll
            for (int k = 0; k < 8; ++k) sb16[k] = f2bf(sv[k]);
            *(bf16x8*)&a0b[j - i0][HK_] = *(const bf16x8*)sb16;
        }
    } else {
        // Q projection (bf16, pre-scaled 1/sqrt(8)): 6 cols of one row
        const int t2 = tid - 256;
        const int il = t2 >> 2;               // 0..63
        const int c0 = (t2 & 3) * 6;
        const float4 s0 = *(const float4*)(sb + (i0+il)*8);
        const float4 s1 = *(const float4*)(sb + (i0+il)*8 + 4);
        const float sv[8] = {s0.x,s0.y,s0.z,s0.w,s1.x,s1.y,s1.z,s1.w};
        #pragma unroll
        for (int cc = 0; cc < 6; ++cc) {
            const int col = c0 + cc;
            float aq = 0.f;
            #pragma unroll
            for (int m = 0; m < K_; ++m) aq = fmaf(sv[m], wq_s[m*HK_+col], aq);
            qh.Qb[il][col] = f2bf(aq * 0.35355339059327373f);
        }
    }
    __syncthreads();                                   // barrier 2

    // ================= row-group phase: rows rw..rw+16 =================
    const int rw = g*16;
    Arena* ar = &arena[g];

    // ---- S = Q@K^T (12 MFMAs/wave: j-half), exp+mask, P->arena, partial sums ----
    {
        const bf16x8 zf = {0,0,0,0,0,0,0,0};
        const f32x4 c0v = {0.f,0.f,0.f,0.f};
        float esum[H_][4];
        #pragma unroll
        for (int h = 0; h < H_; ++h)
            #pragma unroll
            for (int r = 0; r < 4; ++r) esum[h][r] = 0.f;
        #pragma unroll
        for (int h = 0; h < H_; ++h) {
            const bf16x8 tq = *(const bf16x8*)&qh.Qb[rw + ln][h*8];
            const bf16x8 qa = (lq == 0) ? tq : zf;
            #pragma unroll
            for (int nt = 0; nt < 4; ++nt) {
                const int ntt = c*4 + nt;
                const bf16x8 tb = *(const bf16x8*)&Kb[h][ntt*16 + ln][0];
                const bf16x8 kf = (lq == 0) ? tb : zf;
                f32x4 s = __builtin_amdgcn_mfma_f32_16x16x32_bf16(qa, kf, c0v, 0,0,0);
                #pragma unroll
                for (int r = 0; r < 4; ++r) {
                    const int rl = lq*4 + r;             // row within group tile
                    const int j  = ntt*16 + ln;
                    const float e = (j == i0 + rw + rl) ? 0.f : __expf(s[r]);
                    esum[h][r] += e;
                    ar->P[rl][j] = f2bf(e);
                }
            }
        }
        #pragma unroll
        for (int h = 0; h < H_; ++h)
            #pragma unroll
            for (int r = 0; r < 4; ++r) {
                const float v = red16(esum[h][r]);
                if (ln == 0) lsw[g][c][h][lq*4 + r] = v;
            }
    }
    __syncthreads();                  // barrier 2b: both P halves + lsw ready

    // ---- X = P@V; c=0 -> heads {0,1} (8 MFMAs), c=1 -> head {2} (4 MFMAs) ----
    {
        const bf16x8 zf = {0,0,0,0,0,0,0,0};
        const int hbeg = c ? 2 : 0;
        const int hcnt = c ? 1 : 2;
        for (int hi = 0; hi < hcnt; ++hi) {
            const int h = hbeg + hi;
            f32x4 x = {0.f,0.f,0.f,0.f};
            #pragma unroll
            for (int ks = 0; ks < 4; ++ks) {
                const bf16x8 pa = *(const bf16x8*)&ar->P[ln][ks*32 + lq*8];
                const bf16x8 tv = *(const bf16x8*)&Vt[h][ln & 7][ks*32 + lq*8];
                const bf16x8 vf = (ln < 8) ? tv : zf;
                x = __builtin_amdgcn_mfma_f32_16x16x32_bf16(pa, vf, x, 0, 0, 0);
            }
            if (ln < 8) {
                #pragma unroll
                for (int r = 0; r < 4; ++r) {
                    const int rl = lq*4 + r;
                    const float l = lsw[g][0][h][rl] + lsw[g][1][h][rl];
                    const float xatt = x[r] / l - bf2f(Vt[h][ln][i0 + rw + rl]);
                    a0b[rw + rl][h*8 + ln] = f2bf(xatt);
                }
            }
        }
    }

    // ---- acquire producer flags (prep overlapped attention) ----
    if (tid < NPROD_) {
        while (__hip_atomic_load(&flags[tid], __ATOMIC_ACQUIRE,
                                 __HIP_MEMORY_SCOPE_AGENT) != 1u) {
            __builtin_amdgcn_s_sleep(1);
        }
    }
    __syncthreads();                  // barrier 3 (flags + a0b + arena reuse)

    // ---- x1 = relu([x||state] @ W1 + b1): 8 MFMAs/wave (N-half) ----
    {
        bf16x8 w1f[8];
        #pragma unroll
        for (int nt = 0; nt < 8; ++nt)
            w1f[nt] = *(const bf16x8*)(w1t + (size_t)((c*8+nt)*16+ln)*32 + lq*8);
        const bf16x8 a0 = *(const bf16x8*)&a0b[rw + ln][lq*8];
        #pragma unroll
        for (int nt = 0; nt < 8; ++nt) {
            const float bias = b1v[nt];
            f32x4 cc = {bias, bias, bias, bias};
            f32x4 d = __builtin_amdgcn_mfma_f32_16x16x32_bf16(a0, w1f[nt], cc, 0, 0, 0);
            #pragma unroll
            for (int r = 0; r < 4; ++r)
                ar->x1[lq*4 + r][(c*8+nt)*16 + ln] = f2bf(fmaxf(d[r], 0.f));
        }
    }
    __syncthreads();                                   // barrier 4

    // ---- x2 = relu(x1 @ W2 + b2): M=64 (4 m-tiles), wave's N=32 slice ----
    f32x4 acc2[4][2];                      // [mt][nt]
    #pragma unroll
    for (int nt = 0; nt < 2; ++nt) {
        const float bias = b2v[nt];
        f32x4 cc = {bias, bias, bias, bias};
        #pragma unroll
        for (int mt = 0; mt < 4; ++mt) acc2[mt][nt] = cc;
    }
    #pragma unroll
    for (int ks = 0; ks < 8; ++ks) {
        bf16x8 a[4];
        #pragma unroll
        for (int mt = 0; mt < 4; ++mt)
            a[mt] = *(const bf16x8*)&arena[mt].x1[ln][ks*32 + lq*8];
        #pragma unroll
        for (int nt = 0; nt < 2; ++nt) {
            const bf16x8 bf = *(const bf16x8*)(w2t + (size_t)((w*2+nt)*16+ln)*256 + ks*32 + lq*8);
            #pragma unroll
            for (int mt = 0; mt < 4; ++mt)
                acc2[mt][nt] = __builtin_amdgcn_mfma_f32_16x16x32_bf16(a[mt], bf, acc2[mt][nt], 0,0,0);
        }
    }

    // ---- heads: relu(x2).{Wmu,Wls}; DPP 16-lane reduce over n-lanes ----
    {
        float p[4][4][4];                  // [mt][r][o]
        #pragma unroll
        for (int mt = 0; mt < 4; ++mt)
            #pragma unroll
            for (int r = 0; r < 4; ++r)
                #pragma unroll
                for (int o = 0; o < 4; ++o) p[mt][r][o] = 0.f;
        #pragma unroll
        for (int nt = 0; nt < 2; ++nt) {
            const float2 wm = wmv[nt];
            const float2 wl = wlv[nt];
            #pragma unroll
            for (int mt = 0; mt < 4; ++mt) {
                #pragma unroll
                for (int r = 0; r < 4; ++r) {
                    const float x2 = fmaxf(acc2[mt][nt][r], 0.f);
                    p[mt][r][0] = fmaf(x2, wm.x, p[mt][r][0]);
                    p[mt][r][1] = fmaf(x2, wm.y, p[mt][r][1]);
                    p[mt][r][2] = fmaf(x2, wl.x, p[mt][r][2]);
                    p[mt][r][3] = fmaf(x2, wl.y, p[mt][r][3]);
                }
            }
        }
        #pragma unroll
        for (int mt = 0; mt < 4; ++mt)
            #pragma unroll
            for (int r = 0; r < 4; ++r)
                #pragma unroll
                for (int o = 0; o < 4; ++o)
                    p[mt][r][o] = red16(p[mt][r][o]);
        if (ln == 0) {
            #pragma unroll
            for (int mt = 0; mt < 4; ++mt)
                #pragma unroll
                for (int r = 0; r < 4; ++r) {
                    f32x4 pv = {p[mt][r][0], p[mt][r][1], p[mt][r][2], p[mt][r][3]};
                    *(f32x4*)&qh.hp[w][mt*16 + lq*4 + r][0] = pv;
                }
        }
    }
    __syncthreads();                                   // barrier 5

    // ---- sampling tail: one thread per row (fast transcendentals) ----
    if (tid < 64) {
        const int r = tid;
        const int grow = b*T_ + i0 + r;
        float pre[4];
        #pragma unroll
        for (int o = 0; o < 4; ++o) {
            float s = 0.f;
            #pragma unroll
            for (int ww = 0; ww < 8; ++ww) s += qh.hp[ww][r][o];
            pre[o] = s;
        }
        float lp = 0.f;
        #pragma unroll
        for (int o = 0; o < OUT_; ++o) {
            float mu  = ftanh(pre[o]   + bmu[o]);
            float lsp = ftanh(pre[2+o] + bls[o]);
            float log_std = -20.f + 11.f * (lsp + 1.f);
            float sd = __expf(log_std);
            float n  = noise[(size_t)grow*OUT_ + o];
            float z  = fmaf(sd, n, mu);
            float a  = ftanh(z);
            out[(size_t)grow*OUT_ + o] = a;
            lp += -0.5f*n*n - log_std - 0.91893853320467274f
                  - __logf(1.f - a*a + 1e-7f);
        }
        out[(size_t)B_*T_*OUT_ + grow] = lp;
    }
}

extern "C" void kernel_launch(void* const* d_in, const int* in_sizes, int n_in,
                              void* d_out, int out_size, void* d_ws, size_t ws_size,
                              hipStream_t stream)
{
    const float* state = (const float*)d_in[0];
    const float* noise = (const float*)d_in[1];
    const float* Wq  = (const float*)d_in[2];
    const float* Wk  = (const float*)d_in[3];
    const float* Wv  = (const float*)d_in[4];
    const float* W1  = (const float*)d_in[5];
    const float* b1  = (const float*)d_in[6];
    const float* W2  = (const float*)d_in[7];
    const float* b2  = (const float*)d_in[8];
    const float* Wmu = (const float*)d_in[9];
    const float* bmu = (const float*)d_in[10];
    const float* Wls = (const float*)d_in[11];
    const float* bls = (const float*)d_in[12];
    float* out = (float*)d_out;

    unsigned short* w1t = (unsigned short*)d_ws;            // 8192 bf16 = 16 KB
    unsigned short* w2t = w1t + 8192;                       // 65536 bf16 = 128 KB
    unsigned int*  flags = (unsigned int*)(w2t + 65536);    // 17 cells (poison != 1)

    fused_actor_kernel<<<dim3(B_*2), dim3(512), 0, stream>>>(
        state, noise, Wq, Wk, Wv, W1, b1, W2, b2, Wmu, bmu, Wls, bls,
        w1t, w2t, flags, out);
}